// Round 4
// baseline (113.795 us; speedup 1.0000x reference)
//
#include <hip/hip_runtime.h>
#include <hip/hip_bf16.h>

#define BH 16
#define L 2048
#define S 2048
#define DD 64
#define BMB 32               // L-rows per block
#define NPITCH 68            // epilogue LDS pitch (floats), 68%32=4 -> 2-way max
#define LDSPAD 8
#define LDW (DD + LDSPAD)

typedef __attribute__((ext_vector_type(4))) float f32x4;
typedef __bf16 bf16x8 __attribute__((ext_vector_type(8)));

union FragU {
  bf16x8 f;
  __hip_bfloat162 h2[4];
};

__device__ inline __hip_bfloat162 exp2pack(float al2, float nsl2, float k0,
                                           float k1, float& d) {
  float e0 = __builtin_amdgcn_exp2f(fmaf(al2, k0, nsl2));
  float e1 = __builtin_amdgcn_exp2f(fmaf(al2, k1, nsl2));
  d += e0 + e1;
  return __float22bfloat162_rn(make_float2(e0, e1));
}

// ---------------------------------------------------------------------------
// prep: blocks [0,2048): K row sums (16 lanes per row).
//       blocks [2048,2560): V [bh][s][d] fp32 -> tiled VT2 bf16:
//       VT2[head][s/64][d][s%64], 8KB contiguous per 64x64 tile.
//       Transpose blocks use the attn head<->XCD swizzle so tiles are written
//       by the XCD that will read them.
// ---------------------------------------------------------------------------
__global__ __launch_bounds__(256) void prep_kernel(
    const float* __restrict__ k, const float* __restrict__ v,
    float* __restrict__ ks, __hip_bfloat16* __restrict__ vt) {
  __shared__ __hip_bfloat16 tile[DD][LDW];
  int t = threadIdx.x;
  if (blockIdx.x < 2048) {
    int g = blockIdx.x * 256 + t;
    int row = g >> 4;
    int l16 = g & 15;
    float4 x = reinterpret_cast<const float4*>(k + (size_t)row * DD)[l16];
    float s = x.x + x.y + x.z + x.w;
    s += __shfl_xor(s, 1);
    s += __shfl_xor(s, 2);
    s += __shfl_xor(s, 4);
    s += __shfl_xor(s, 8);
    if (l16 == 0) ks[row] = s;
  } else {
    int bid = blockIdx.x - 2048;
    // head such that head>>1 == XCD of this block (round-robin by linear id)
    int bh = (bid & 7) * 2 + ((bid >> 3) & 1);
    int st = bid >> 4;        // s-tile 0..31
    int s0 = st * 64;
    int srow = t >> 4;
    int d4 = (t & 15) * 4;
#pragma unroll
    for (int kk = 0; kk < 4; ++kk) {
      int s = srow + kk * 16;
      float4 val = *reinterpret_cast<const float4*>(
          v + ((size_t)(bh * S + s0 + s)) * DD + d4);
      tile[d4 + 0][s] = __float2bfloat16(val.x);
      tile[d4 + 1][s] = __float2bfloat16(val.y);
      tile[d4 + 2][s] = __float2bfloat16(val.z);
      tile[d4 + 3][s] = __float2bfloat16(val.w);
    }
    __syncthreads();
    __hip_bfloat16* tb = vt + ((size_t)(bh * 32 + st)) * (DD * 64);
    int dd = t >> 3;
    int j = t & 7;
#pragma unroll
    for (int kk = 0; kk < 2; ++kk) {
      int d = dd + kk * 32;
      uint4 val = *reinterpret_cast<const uint4*>(&tile[d][j * 8]);
      *reinterpret_cast<uint4*>(tb + d * 64 + j * 8) = val;  // contiguous tile
    }
  }
}

// ---------------------------------------------------------------------------
// attn: block = 32 L-rows of one head (head decoded with XCD swizzle: each
// XCD touches only 2 heads -> VT2+ksum L2-resident). Wave w owns S-quarter
// [w*512,(w+1)*512): K-loop barrier-free & LDS-free, E in A-frag registers,
// B-frags from tiled VT2 (contiguous 8KB tiles, no power-of-2 stride).
// Per-wave partials combined once through LDS at the end.
// ---------------------------------------------------------------------------
__global__ __launch_bounds__(256, 4) void attn_kernel(
    const float* __restrict__ q, const __hip_bfloat16* __restrict__ vt,
    const float* __restrict__ ks, float* __restrict__ out) {
  int lin = blockIdx.x;
  int bh = (lin & 7) * 2 + ((lin >> 3) & 1);
  int l0 = (lin >> 4) * BMB;

  __shared__ float numLDS[4][BMB][NPITCH];
  __shared__ float dLDS[4][BMB];
  __shared__ float a_row[BMB];
  __shared__ float red[16];

  int t = threadIdx.x;
  int lane = t & 63;
  int w = t >> 6;
  int m = lane & 15;
  int qd = lane >> 4;

  const float* ksb = ks + (size_t)bh * S;
  const __hip_bfloat16* tb = vt + ((size_t)bh * 32) * (DD * 64);

  // --- qsum for this block's 32 rows: 8 lanes per row
  {
    int r = t >> 3;
    int p = t & 7;
    const float* qp = q + ((size_t)(bh * L + l0 + r)) * DD + p * 8;
    float4 x0 = reinterpret_cast<const float4*>(qp)[0];
    float4 x1 = reinterpret_cast<const float4*>(qp)[1];
    float s = (x0.x + x0.y + x0.z + x0.w) + (x1.x + x1.y + x1.z + x1.w);
    s += __shfl_xor(s, 1);
    s += __shfl_xor(s, 2);
    s += __shfl_xor(s, 4);
    if (p == 0) a_row[r] = s;
  }
  // --- per-head kmax/kmin (identical in every block of this head)
  {
    const float* kp = ksb + t * 8;
    float4 y0 = reinterpret_cast<const float4*>(kp)[0];
    float4 y1 = reinterpret_cast<const float4*>(kp)[1];
    float mx = fmaxf(fmaxf(fmaxf(y0.x, y0.y), fmaxf(y0.z, y0.w)),
                     fmaxf(fmaxf(y1.x, y1.y), fmaxf(y1.z, y1.w)));
    float mn = fminf(fminf(fminf(y0.x, y0.y), fminf(y0.z, y0.w)),
                     fminf(fminf(y1.x, y1.y), fminf(y1.z, y1.w)));
#pragma unroll
    for (int off = 1; off < 64; off <<= 1) {
      mx = fmaxf(mx, __shfl_xor(mx, off));
      mn = fminf(mn, __shfl_xor(mn, off));
    }
    if (lane == 0) {
      red[w] = mx;
      red[8 + w] = mn;
    }
  }
  __syncthreads();

  float kmax = fmaxf(fmaxf(red[0], red[1]), fmaxf(red[2], red[3]));
  float kmin = fminf(fminf(red[8], red[9]), fminf(red[10], red[11]));
  const float LOG2E = 1.44269504088896f;
  float ar0 = a_row[m];       // A-frag rows 0..15
  float ar1 = a_row[16 + m];  // A-frag rows 16..31
  float al20 = ar0 * LOG2E, al21 = ar1 * LOG2E;
  float nsl20 = -al20 * ((ar0 > 0.f) ? kmax : kmin);
  float nsl21 = -al21 * ((ar1 > 0.f) ? kmax : kmin);

  f32x4 acc[2][4];
#pragma unroll
  for (int a = 0; a < 2; ++a)
#pragma unroll
    for (int c = 0; c < 4; ++c) acc[a][c] = (f32x4){0.f, 0.f, 0.f, 0.f};
  float ds0 = 0.f, ds1 = 0.f;

  int sw = w * (S / 4);
#pragma unroll 2
  for (int kt = 0; kt < (S / 4) / 32; ++kt) {
    int sb = sw + kt * 32;
    const __hip_bfloat16* tp =
        tb + (size_t)(sb >> 6) * (DD * 64) + (sb & 63) + qd * 8;
    // B-frags: 64B segments inside one contiguous 8KB tile
    uint4 b0 = *reinterpret_cast<const uint4*>(tp + (0 * 16 + m) * 64);
    uint4 b1 = *reinterpret_cast<const uint4*>(tp + (1 * 16 + m) * 64);
    uint4 b2 = *reinterpret_cast<const uint4*>(tp + (2 * 16 + m) * 64);
    uint4 b3 = *reinterpret_cast<const uint4*>(tp + (3 * 16 + m) * 64);
    float4 kv0 = *reinterpret_cast<const float4*>(ksb + sb + qd * 8);
    float4 kv1 = *reinterpret_cast<const float4*>(ksb + sb + qd * 8 + 4);

    FragU e0, e1;  // A-frags for row-tiles 0 and 1
    e0.h2[0] = exp2pack(al20, nsl20, kv0.x, kv0.y, ds0);
    e0.h2[1] = exp2pack(al20, nsl20, kv0.z, kv0.w, ds0);
    e0.h2[2] = exp2pack(al20, nsl20, kv1.x, kv1.y, ds0);
    e0.h2[3] = exp2pack(al20, nsl20, kv1.z, kv1.w, ds0);
    e1.h2[0] = exp2pack(al21, nsl21, kv0.x, kv0.y, ds1);
    e1.h2[1] = exp2pack(al21, nsl21, kv0.z, kv0.w, ds1);
    e1.h2[2] = exp2pack(al21, nsl21, kv1.x, kv1.y, ds1);
    e1.h2[3] = exp2pack(al21, nsl21, kv1.z, kv1.w, ds1);

    acc[0][0] = __builtin_amdgcn_mfma_f32_16x16x32_bf16(
        e0.f, __builtin_bit_cast(bf16x8, b0), acc[0][0], 0, 0, 0);
    acc[0][1] = __builtin_amdgcn_mfma_f32_16x16x32_bf16(
        e0.f, __builtin_bit_cast(bf16x8, b1), acc[0][1], 0, 0, 0);
    acc[0][2] = __builtin_amdgcn_mfma_f32_16x16x32_bf16(
        e0.f, __builtin_bit_cast(bf16x8, b2), acc[0][2], 0, 0, 0);
    acc[0][3] = __builtin_amdgcn_mfma_f32_16x16x32_bf16(
        e0.f, __builtin_bit_cast(bf16x8, b3), acc[0][3], 0, 0, 0);
    acc[1][0] = __builtin_amdgcn_mfma_f32_16x16x32_bf16(
        e1.f, __builtin_bit_cast(bf16x8, b0), acc[1][0], 0, 0, 0);
    acc[1][1] = __builtin_amdgcn_mfma_f32_16x16x32_bf16(
        e1.f, __builtin_bit_cast(bf16x8, b1), acc[1][1], 0, 0, 0);
    acc[1][2] = __builtin_amdgcn_mfma_f32_16x16x32_bf16(
        e1.f, __builtin_bit_cast(bf16x8, b2), acc[1][2], 0, 0, 0);
    acc[1][3] = __builtin_amdgcn_mfma_f32_16x16x32_bf16(
        e1.f, __builtin_bit_cast(bf16x8, b3), acc[1][3], 0, 0, 0);
  }

  // per-wave row denominators (lanes m, m+16, m+32, m+48 share a row)
  ds0 += __shfl_xor(ds0, 16);
  ds0 += __shfl_xor(ds0, 32);
  ds1 += __shfl_xor(ds1, 16);
  ds1 += __shfl_xor(ds1, 32);
  if (qd == 0) {
    dLDS[w][m] = ds0;
    dLDS[w][16 + m] = ds1;
  }
  // per-wave partial numerators (C layout: col=lane&15, row=quad*4+reg)
#pragma unroll
  for (int a = 0; a < 2; ++a)
#pragma unroll
    for (int c = 0; c < 4; ++c)
#pragma unroll
      for (int i = 0; i < 4; ++i)
        numLDS[w][a * 16 + qd * 4 + i][c * 16 + m] = acc[a][c][i];
  __syncthreads();

  // combine 4 waves + normalize + coalesced store
  {
    int r = t >> 3;
    int cg = (t & 7) * 8;
    float4 n0 = *reinterpret_cast<const float4*>(&numLDS[0][r][cg]);
    float4 n1 = *reinterpret_cast<const float4*>(&numLDS[0][r][cg + 4]);
#pragma unroll
    for (int ww = 1; ww < 4; ++ww) {
      float4 p0 = *reinterpret_cast<const float4*>(&numLDS[ww][r][cg]);
      float4 p1 = *reinterpret_cast<const float4*>(&numLDS[ww][r][cg + 4]);
      n0.x += p0.x; n0.y += p0.y; n0.z += p0.z; n0.w += p0.w;
      n1.x += p1.x; n1.y += p1.y; n1.z += p1.z; n1.w += p1.w;
    }
    float inv = 1.0f / (dLDS[0][r] + dLDS[1][r] + dLDS[2][r] + dLDS[3][r]);
    n0.x *= inv; n0.y *= inv; n0.z *= inv; n0.w *= inv;
    n1.x *= inv; n1.y *= inv; n1.z *= inv; n1.w *= inv;
    float* ob = out + ((size_t)(bh * L + l0 + r)) * DD + cg;
    reinterpret_cast<float4*>(ob)[0] = n0;
    reinterpret_cast<float4*>(ob)[1] = n1;
  }
}

extern "C" void kernel_launch(void* const* d_in, const int* in_sizes, int n_in,
                              void* d_out, int out_size, void* d_ws,
                              size_t ws_size, hipStream_t stream) {
  const float* q = (const float*)d_in[0];
  const float* k = (const float*)d_in[1];
  const float* v = (const float*)d_in[2];
  float* out = (float*)d_out;
  float* ws = (float*)d_ws;

  float* ks = ws;  // BH*S = 32768 floats
  __hip_bfloat16* vt = (__hip_bfloat16*)(ws + BH * S);  // tiled VT2, 4MB

  prep_kernel<<<2048 + 512, 256, 0, stream>>>(k, v, ks, vt);
  attn_kernel<<<(L / BMB) * BH, 256, 0, stream>>>(q, vt, ks, out);
}

// Round 5
// 100.297 us; speedup vs baseline: 1.1346x; 1.1346x over previous
//
#include <hip/hip_runtime.h>
#include <hip/hip_bf16.h>

#define BH 16
#define L 2048
#define S 2048
#define DD 64
#define BM 64
#define BK 64
#define LDSPAD 8
#define LDW (BK + LDSPAD)   // 72 elements -> 144B row stride, 16B aligned

typedef __attribute__((ext_vector_type(4))) float f32x4;
typedef __bf16 bf16x8 __attribute__((ext_vector_type(8)));

union FragU {
  bf16x8 f;
  __hip_bfloat162 h2[4];
};

__device__ inline __hip_bfloat162 exp2pack(float al2, float nsl2, float k0,
                                           float k1, float& d) {
  float e0 = __builtin_amdgcn_exp2f(fmaf(al2, k0, nsl2));
  float e1 = __builtin_amdgcn_exp2f(fmaf(al2, k1, nsl2));
  d += e0 + e1;
  return __float22bfloat162_rn(make_float2(e0, e1));
}

// ---------------------------------------------------------------------------
// prep: blocks [0,2048): K row sums (16 lanes per row).
//       blocks [2048,2560): V [bh][s][d] fp32 -> tiled VT2 bf16:
//       VT2[head][s/64][d][s%64], 8KB contiguous per 64x64 tile. Heads
//       swizzled so writer XCD == reader XCD (if round-robin dispatch holds).
// ---------------------------------------------------------------------------
__global__ __launch_bounds__(256) void prep_kernel(
    const float* __restrict__ k, const float* __restrict__ v,
    float* __restrict__ ks, __hip_bfloat16* __restrict__ vt) {
  __shared__ __hip_bfloat16 tile[DD][LDW];
  int t = threadIdx.x;
  if (blockIdx.x < 2048) {
    int g = blockIdx.x * 256 + t;
    int row = g >> 4;
    int l16 = g & 15;
    float4 x = reinterpret_cast<const float4*>(k + (size_t)row * DD)[l16];
    float s = x.x + x.y + x.z + x.w;
    s += __shfl_xor(s, 1);
    s += __shfl_xor(s, 2);
    s += __shfl_xor(s, 4);
    s += __shfl_xor(s, 8);
    if (l16 == 0) ks[row] = s;
  } else {
    int bid = blockIdx.x - 2048;
    int bh = (bid & 7) * 2 + ((bid >> 3) & 1);
    int st = bid >> 4;        // s-tile 0..31
    int s0 = st * 64;
    int srow = t >> 4;
    int d4 = (t & 15) * 4;
#pragma unroll
    for (int kk = 0; kk < 4; ++kk) {
      int s = srow + kk * 16;
      float4 val = *reinterpret_cast<const float4*>(
          v + ((size_t)(bh * S + s0 + s)) * DD + d4);
      tile[d4 + 0][s] = __float2bfloat16(val.x);
      tile[d4 + 1][s] = __float2bfloat16(val.y);
      tile[d4 + 2][s] = __float2bfloat16(val.z);
      tile[d4 + 3][s] = __float2bfloat16(val.w);
    }
    __syncthreads();
    __hip_bfloat16* tb = vt + ((size_t)(bh * 32 + st)) * (DD * 64);
    int dd = t >> 3;
    int j = t & 7;
#pragma unroll
    for (int kk = 0; kk < 2; ++kk) {
      int d = dd + kk * 32;
      uint4 val = *reinterpret_cast<const uint4*>(&tile[d][j * 8]);
      *reinterpret_cast<uint4*>(tb + d * 64 + j * 8) = val;  // contiguous tile
    }
  }
}

// ---------------------------------------------------------------------------
// attn (round-2 structure, measured best): block = 64 L-rows of one head.
// Double-buffered LDS VT tile, register prefetch, ONE barrier per 64-k tile.
// E generated per-lane in A-fragment registers (no LDS for E). Staging loads
// are contiguous 4KB segments from tiled VT2. No launch_bounds min-waves
// (rounds 3/4 regressed with (256,4) -> suspected register-cap spills).
// ---------------------------------------------------------------------------
__global__ __launch_bounds__(256) void attn_kernel(
    const float* __restrict__ q, const __hip_bfloat16* __restrict__ vt,
    const float* __restrict__ ks, float* __restrict__ out) {
  int bx = blockIdx.x;
  int bh = (bx & 7) * 2 + ((bx >> 3) & 1);  // XCD swizzle: 2 heads per XCD
  int l0 = (bx >> 4) * BM;

  __shared__ __hip_bfloat16 ldsVT[2][DD][LDW];
  __shared__ float a_row[BM];
  __shared__ float red[16];

  int t = threadIdx.x;
  int lane = t & 63;
  int w = t >> 6;
  int m = lane & 15;
  int qd = lane >> 4;  // quad 0..3

  const __hip_bfloat16* vtb = vt + ((size_t)bh * 32) * (DD * 64);
  const float* ksb = ks + (size_t)bh * S;

  // --- prologue global prefetch: VT tile 0 (contiguous) + ksum chunk 0
  uint4 v0 = *reinterpret_cast<const uint4*>(vtb + t * 8);
  uint4 v1 = *reinterpret_cast<const uint4*>(vtb + 2048 + t * 8);
  float4 kA0 = *reinterpret_cast<const float4*>(ksb + qd * 8);
  float4 kA1 = *reinterpret_cast<const float4*>(ksb + qd * 8 + 4);
  float4 kB0 = *reinterpret_cast<const float4*>(ksb + 32 + qd * 8);
  float4 kB1 = *reinterpret_cast<const float4*>(ksb + 32 + qd * 8 + 4);

  // --- qsum for this block's 64 rows: 4 lanes per row
  {
    int r = t >> 2;
    int p = t & 3;
    const float* qp = q + ((size_t)(bh * L + l0 + r)) * DD + p * 16;
    float4 x0 = reinterpret_cast<const float4*>(qp)[0];
    float4 x1 = reinterpret_cast<const float4*>(qp)[1];
    float4 x2 = reinterpret_cast<const float4*>(qp)[2];
    float4 x3 = reinterpret_cast<const float4*>(qp)[3];
    float s = (x0.x + x0.y + x0.z + x0.w) + (x1.x + x1.y + x1.z + x1.w) +
              (x2.x + x2.y + x2.z + x2.w) + (x3.x + x3.y + x3.z + x3.w);
    s += __shfl_xor(s, 1);
    s += __shfl_xor(s, 2);
    if (p == 0) a_row[r] = s;
  }

  // --- per-head kmax/kmin (identical in every block of this head)
  {
    const float* kp = ksb + t * 8;
    float4 y0 = reinterpret_cast<const float4*>(kp)[0];
    float4 y1 = reinterpret_cast<const float4*>(kp)[1];
    float mx = fmaxf(fmaxf(fmaxf(y0.x, y0.y), fmaxf(y0.z, y0.w)),
                     fmaxf(fmaxf(y1.x, y1.y), fmaxf(y1.z, y1.w)));
    float mn = fminf(fminf(fminf(y0.x, y0.y), fminf(y0.z, y0.w)),
                     fminf(fminf(y1.x, y1.y), fminf(y1.z, y1.w)));
#pragma unroll
    for (int off = 1; off < 64; off <<= 1) {
      mx = fmaxf(mx, __shfl_xor(mx, off));
      mn = fminf(mn, __shfl_xor(mn, off));
    }
    if (lane == 0) {
      red[w] = mx;
      red[8 + w] = mn;
    }
  }
  __syncthreads();

  float kmax = fmaxf(fmaxf(red[0], red[1]), fmaxf(red[2], red[3]));
  float kmin = fminf(fminf(red[8], red[9]), fminf(red[10], red[11]));
  float ar = a_row[w * 16 + m];  // this lane's E-row coefficient
  float sel = (ar > 0.f) ? kmax : kmin;
  const float LOG2E = 1.44269504088896f;
  float al2 = ar * LOG2E;
  float nsl2 = -al2 * sel;

  float dsum = 0.f;
  f32x4 acc[4];
#pragma unroll
  for (int c = 0; c < 4; ++c) acc[c] = (f32x4){0.f, 0.f, 0.f, 0.f};

  for (int it = 0; it < 32; ++it) {
    int bufi = it & 1;
    // store prefetched VT tile: element e = t*8 -> d=e>>6, s=e&63
    *reinterpret_cast<uint4*>(&ldsVT[bufi][t >> 3][(t & 7) * 8]) = v0;
    *reinterpret_cast<uint4*>(&ldsVT[bufi][32 + (t >> 3)][(t & 7) * 8]) = v1;
    __syncthreads();  // the ONLY barrier per tile

    int itn = (it < 31) ? it + 1 : 31;  // clamped prefetch
    const __hip_bfloat16* tn = vtb + (size_t)itn * (DD * 64);
    v0 = *reinterpret_cast<const uint4*>(tn + t * 8);
    v1 = *reinterpret_cast<const uint4*>(tn + 2048 + t * 8);
    int s0n = itn * BK;

    // E fragments in registers (A-layout: row m, k = kk*32 + qd*8 + j)
    FragU f0, f1;
    f0.h2[0] = exp2pack(al2, nsl2, kA0.x, kA0.y, dsum);
    f0.h2[1] = exp2pack(al2, nsl2, kA0.z, kA0.w, dsum);
    f0.h2[2] = exp2pack(al2, nsl2, kA1.x, kA1.y, dsum);
    f0.h2[3] = exp2pack(al2, nsl2, kA1.z, kA1.w, dsum);
    f1.h2[0] = exp2pack(al2, nsl2, kB0.x, kB0.y, dsum);
    f1.h2[1] = exp2pack(al2, nsl2, kB0.z, kB0.w, dsum);
    f1.h2[2] = exp2pack(al2, nsl2, kB1.x, kB1.y, dsum);
    f1.h2[3] = exp2pack(al2, nsl2, kB1.z, kB1.w, dsum);

    // prefetch next ksum chunk
    kA0 = *reinterpret_cast<const float4*>(ksb + s0n + qd * 8);
    kA1 = *reinterpret_cast<const float4*>(ksb + s0n + qd * 8 + 4);
    kB0 = *reinterpret_cast<const float4*>(ksb + s0n + 32 + qd * 8);
    kB1 = *reinterpret_cast<const float4*>(ksb + s0n + 32 + qd * 8 + 4);

    // MFMA: wave computes rows [w*16, w*16+16) x 64 cols
#pragma unroll
    for (int c = 0; c < 4; ++c) {
      uint4 bu0 =
          *reinterpret_cast<const uint4*>(&ldsVT[bufi][c * 16 + m][qd * 8]);
      acc[c] = __builtin_amdgcn_mfma_f32_16x16x32_bf16(
          f0.f, __builtin_bit_cast(bf16x8, bu0), acc[c], 0, 0, 0);
      uint4 bu1 = *reinterpret_cast<const uint4*>(
          &ldsVT[bufi][c * 16 + m][32 + qd * 8]);
      acc[c] = __builtin_amdgcn_mfma_f32_16x16x32_bf16(
          f1.f, __builtin_bit_cast(bf16x8, bu1), acc[c], 0, 0, 0);
    }
  }

  // row denominators: lanes {m, m+16, m+32, m+48} hold partial sums of row m
  float dt = dsum;
  dt += __shfl_xor(dt, 16);
  dt += __shfl_xor(dt, 32);
  float inv[4];
#pragma unroll
  for (int i = 0; i < 4; ++i) inv[i] = 1.0f / __shfl(dt, qd * 4 + i);

  // C layout: col = lane&15, row = quad*4 + reg
  float* ob = out + ((size_t)(bh * L + l0 + w * 16)) * DD;
#pragma unroll
  for (int c = 0; c < 4; ++c) {
#pragma unroll
    for (int i = 0; i < 4; ++i) {
      ob[(size_t)(qd * 4 + i) * DD + c * 16 + m] = acc[c][i] * inv[i];
    }
  }
}

extern "C" void kernel_launch(void* const* d_in, const int* in_sizes, int n_in,
                              void* d_out, int out_size, void* d_ws,
                              size_t ws_size, hipStream_t stream) {
  const float* q = (const float*)d_in[0];
  const float* k = (const float*)d_in[1];
  const float* v = (const float*)d_in[2];
  float* out = (float*)d_out;
  float* ws = (float*)d_ws;

  float* ks = ws;  // BH*S = 32768 floats
  __hip_bfloat16* vt = (__hip_bfloat16*)(ws + BH * S);  // tiled VT2, 4MB

  prep_kernel<<<2048 + 512, 256, 0, stream>>>(k, v, ks, vt);
  attn_kernel<<<(L / BM) * BH, 256, 0, stream>>>(q, vt, ks, out);
}